// Round 2
// baseline (152.098 us; speedup 1.0000x reference)
//
#include <hip/hip_runtime.h>

#define S_DIM 363      // GRID = ceil(sqrt(2)*256)
#define A_DIM 180      // N_THETA
#define N_BATCH 4
#define OUT_W 256
#define F_PI 3.14159265358979323846f

// Intermediate filtered sinogram, laid out (N, A, S), contiguous in s.
// Static device global: avoids any dependence on ws_size (suspected cause of
// the round-1 GPU memory fault), no hipMalloc needed, graph-capture safe.
// Fully overwritten by the filter kernel on every call before being read.
__device__ float g_yf[N_BATCH * A_DIM * S_DIM];

// ---------------------------------------------------------------------------
// Kernel 1: ramp filter as direct spatial convolution.
// The reference's FFT path (pad to P=1024, multiply by 2*Re(FFT(f)), IFFT,
// crop to S) is exactly circular convolution with g[m] = f[m] + f[P-m]:
//   g[0] = 0.5, g[m] = -2/(pi*d)^2 for odd d=min(m,P-m), else 0.
// For t,s in [0,363), |t-s| <= 362 < 512, so weight depends only on |t-s|.
// Input layout  x[n, 0, s, a]  (stride A_DIM over s)
// Output layout g_yf[n, a, s]  (contiguous in s -> coalesced reads in kernel 2)
// ---------------------------------------------------------------------------
__global__ __launch_bounds__(256) void iradon_filter_kernel(
        const float* __restrict__ x) {
    __shared__ float xs[S_DIM];
    __shared__ float wt[S_DIM];

    const int b = blockIdx.x;        // 0 .. N_BATCH*A_DIM-1
    const int n = b / A_DIM;
    const int a = b % A_DIM;
    const int tid = threadIdx.x;

    // stage the detector column for this (batch, angle)
    for (int s = tid; s < S_DIM; s += 256)
        xs[s] = x[(n * S_DIM + s) * A_DIM + a];

    // ramp weights w(d)
    for (int d = tid; d < S_DIM; d += 256) {
        float w;
        if (d == 0)      w = 0.5f;
        else if (d & 1)  w = -2.0f / (F_PI * F_PI * (float)d * (float)d);
        else             w = 0.0f;
        wt[d] = w;
    }
    __syncthreads();

    for (int t = tid; t < S_DIM; t += 256) {
        float acc = 0.0f;
        #pragma unroll 4
        for (int s = 0; s < S_DIM; ++s) {
            int d = t - s; d = (d < 0) ? -d : d;
            acc += xs[s] * wt[d];
        }
        g_yf[(n * A_DIM + a) * S_DIM + t] = acc;
    }
}

// ---------------------------------------------------------------------------
// Kernel 2: backprojection over 180 angles with 2-point linear interpolation.
// Output pixel (i,j) of the 256x256 crop maps to full-grid (i+53, j+53);
// with unit[k] = (k-181)/181 this gives
//   pos = (j-128)*cos(th) - (i-128)*sin(th) + 181.
// Out-of-range taps get zero weight (matches reference clip+mask semantics).
// ---------------------------------------------------------------------------
__global__ __launch_bounds__(256) void iradon_backproject_kernel(
        float* __restrict__ out) {
    __shared__ float cs[A_DIM];
    __shared__ float sn[A_DIM];

    const int tid = threadIdx.x;
    if (tid < A_DIM) {
        float th = (float)tid * (F_PI / 180.0f);
        cs[tid] = cosf(th);
        sn[tid] = sinf(th);
    }
    __syncthreads();

    const int n = blockIdx.z;
    const int i = blockIdx.y * 16 + (tid >> 4);
    const int j = blockIdx.x * 16 + (tid & 15);

    const float jj = (float)(j - 128);
    const float ii = (float)(i - 128);

    const float* __restrict__ yn = g_yf + (size_t)n * A_DIM * S_DIM;

    float acc = 0.0f;
    for (int a = 0; a < A_DIM; ++a) {
        float pos = jj * cs[a] - ii * sn[a] + 181.0f;
        float f0  = floorf(pos);
        int   i0  = (int)f0;
        float w   = pos - f0;
        const float* __restrict__ col = yn + a * S_DIM;
        float v = 0.0f;
        if (i0 >= 0 && i0 < S_DIM)           v += (1.0f - w) * col[i0];
        if (i0 + 1 >= 0 && i0 + 1 < S_DIM)   v += w * col[i0 + 1];
        acc += v;
    }

    out[((size_t)n * OUT_W + i) * OUT_W + j] = acc * (F_PI / 360.0f);
}

extern "C" void kernel_launch(void* const* d_in, const int* in_sizes, int n_in,
                              void* d_out, int out_size, void* d_ws, size_t ws_size,
                              hipStream_t stream) {
    const float* x = (const float*)d_in[0];
    float* out = (float*)d_out;

    iradon_filter_kernel<<<dim3(N_BATCH * A_DIM), 256, 0, stream>>>(x);
    iradon_backproject_kernel<<<dim3(OUT_W / 16, OUT_W / 16, N_BATCH), 256, 0, stream>>>(out);
}

// Round 3
// 88.364 us; speedup vs baseline: 1.7213x; 1.7213x over previous
//
#include <hip/hip_runtime.h>

#define S_DIM 363      // GRID = ceil(sqrt(2)*256)
#define S_P   368      // padded stride: guard zero at [0], data at [1..363], zeros at [364..367]
#define A_DIM 180      // N_THETA
#define N_BATCH 4
#define OUT_W 256
#define F_PI 3.14159265358979323846f

// Filtered sinogram, (N, A, S_P) with zero guards so backprojection needs no
// bounds checks: pos in [-0.02, 362.02] => i0 in [-1,362] => indices i0+1 in
// [0,363], i0+2 in [1,364], all inside [0,368) with [0] and [364] zeroed.
// Fully rewritten (incl. guards) by the filter kernel on every call.
__device__ float g_yf[N_BATCH * A_DIM * S_P];

// ---------------------------------------------------------------------------
// Kernel 1: ramp filter as direct spatial convolution (exact rewrite of the
// reference FFT path: circular conv with g[0]=0.5, g[d]=-2/(pi*d)^2 for odd d,
// 0 for even d; |t-s| <= 362 < 512 so no wraparound).
// Even-lag terms are exactly zero -> iterate only opposite-parity s (2x fewer
// terms). All 4 batches per thread via float4 LDS reads (2 LDS reads / 4 FMA).
// Block = 128 threads = one angle x one 128-wide t-chunk. Grid = 180*3.
// ---------------------------------------------------------------------------
__global__ __launch_bounds__(128) void iradon_filter_kernel(
        const float* __restrict__ x) {
    __shared__ float4 xs4[S_DIM];   // per-s, batch-interleaved
    __shared__ float  wt[182];      // wt[k] = -2/(pi*(2k+1))^2

    const int b     = blockIdx.x;       // 0 .. 180*3-1
    const int a     = b / 3;
    const int chunk = b % 3;
    const int tid   = threadIdx.x;

    for (int s = tid; s < S_DIM; s += 128) {
        float4 v;
        v.x = x[(0 * S_DIM + s) * A_DIM + a];
        v.y = x[(1 * S_DIM + s) * A_DIM + a];
        v.z = x[(2 * S_DIM + s) * A_DIM + a];
        v.w = x[(3 * S_DIM + s) * A_DIM + a];
        xs4[s] = v;
    }
    for (int k = tid; k < 182; k += 128) {
        float d = (float)(2 * k + 1);
        wt[k] = -2.0f / (F_PI * F_PI * d * d);
    }
    __syncthreads();

    const int t = chunk * 128 + tid;
    if (t < S_DIM) {
        float4 xt = xs4[t];
        float a0 = 0.5f * xt.x, a1 = 0.5f * xt.y;
        float a2 = 0.5f * xt.z, a3 = 0.5f * xt.w;
        const int s0 = 1 - (t & 1);          // opposite parity of t
        #pragma unroll 4
        for (int s = s0; s < S_DIM; s += 2) {
            int d = s - t; d = (d < 0) ? -d : d;
            float w  = wt[d >> 1];
            float4 v = xs4[s];
            a0 = fmaf(w, v.x, a0);
            a1 = fmaf(w, v.y, a1);
            a2 = fmaf(w, v.z, a2);
            a3 = fmaf(w, v.w, a3);
        }
        g_yf[(0 * A_DIM + a) * S_P + 1 + t] = a0;
        g_yf[(1 * A_DIM + a) * S_P + 1 + t] = a1;
        g_yf[(2 * A_DIM + a) * S_P + 1 + t] = a2;
        g_yf[(3 * A_DIM + a) * S_P + 1 + t] = a3;
    }

    // zero the guard samples for this angle: per batch, indices 0 and 364..367
    if (chunk == 0 && tid < 20) {
        int n = tid / 5, which = tid % 5;
        int idx = (which == 0) ? 0 : (363 + which);   // 0, 364, 365, 366, 367
        g_yf[(n * A_DIM + a) * S_P + idx] = 0.0f;
    }
}

// ---------------------------------------------------------------------------
// Kernel 2: backprojection, 2 pixels/thread (rows i, i+8), angle loop
// unrolled x2 -> 8 independent, unconditional loads in flight per wave.
// pos = (j-128)*cos - (i-128)*sin + 181; guard padding replaces bounds checks
// (verified equivalent to the reference clip+mask semantics at both edges).
// Block = 256 threads = 32(j) x 8(ti) covering a 32x16 tile. Grid = 8x16x4.
// ---------------------------------------------------------------------------
__global__ __launch_bounds__(256) void iradon_backproject_kernel(
        float* __restrict__ out) {
    __shared__ float cs[A_DIM];
    __shared__ float sn[A_DIM];

    const int tid = threadIdx.x;
    if (tid < A_DIM) {
        float th = (float)tid * (F_PI / 180.0f);
        cs[tid] = cosf(th);
        sn[tid] = sinf(th);
    }
    __syncthreads();

    const int n  = blockIdx.z;
    const int tj = tid & 31;
    const int ti = tid >> 5;
    const int j  = blockIdx.x * 32 + tj;
    const int i  = blockIdx.y * 16 + ti;      // rows i and i+8

    const float jj  = (float)(j - 128);
    const float ii0 = (float)(i - 128);
    const float ii1 = ii0 + 8.0f;

    const float* __restrict__ yn = g_yf + (size_t)n * (A_DIM * S_P);

    float acc0 = 0.0f, acc1 = 0.0f;
    for (int a = 0; a < A_DIM; a += 2) {
        #pragma unroll
        for (int u = 0; u < 2; ++u) {
            const float c = cs[a + u];
            const float s = sn[a + u];
            const float* __restrict__ colp = yn + (a + u) * S_P;
            float base = fmaf(jj, c, 181.0f);
            float p0 = fmaf(-ii0, s, base);
            float p1 = fmaf(-ii1, s, base);
            float f0 = floorf(p0), f1 = floorf(p1);
            int   k0 = (int)f0,   k1 = (int)f1;
            float w0 = p0 - f0,   w1 = p1 - f1;
            float v00 = colp[k0 + 1], v01 = colp[k0 + 2];
            float v10 = colp[k1 + 1], v11 = colp[k1 + 2];
            acc0 += fmaf(w0, v01 - v00, v00);
            acc1 += fmaf(w1, v11 - v10, v10);
        }
    }

    out[((size_t)n * OUT_W + i) * OUT_W + j]       = acc0 * (F_PI / 360.0f);
    out[((size_t)n * OUT_W + i + 8) * OUT_W + j]   = acc1 * (F_PI / 360.0f);
}

extern "C" void kernel_launch(void* const* d_in, const int* in_sizes, int n_in,
                              void* d_out, int out_size, void* d_ws, size_t ws_size,
                              hipStream_t stream) {
    const float* x = (const float*)d_in[0];
    float* out = (float*)d_out;

    iradon_filter_kernel<<<dim3(A_DIM * 3), 128, 0, stream>>>(x);
    iradon_backproject_kernel<<<dim3(OUT_W / 32, OUT_W / 16, N_BATCH), 256, 0, stream>>>(out);
}

// Round 4
// 77.615 us; speedup vs baseline: 1.9596x; 1.1385x over previous
//
#include <hip/hip_runtime.h>

#define S_DIM 363      // GRID = ceil(sqrt(2)*256)
#define S_P   368      // padded stride: guard zero at [0], data at [1..363], zeros at [364..367]
#define A_DIM 180      // N_THETA
#define OUT_W 256
#define F_PI 3.14159265358979323846f

typedef float f4 __attribute__((ext_vector_type(4)));

// Filtered sinogram, batch-packed: g_yf4[a*S_P + s] = {n0,n1,n2,n3} at sample s.
// Zero guards at s=0 and s=364..367 replace all bounds checks in backprojection
// (pos in [-0.02, 362.02] => k=floor(pos) in [-1,362] => s-indices k+1 in [0,363],
// k+2 in [1,364]; guards reproduce the reference's clip+mask semantics exactly).
// Fully rewritten (incl. guards) every call before kernel 2 reads it.
__device__ f4 g_yf4[A_DIM * S_P];

// ---------------------------------------------------------------------------
// Kernel 1: ramp filter as direct spatial convolution (exact rewrite of the
// reference FFT path: circular conv with g[0]=0.5, g[d]=-2/(pi*d)^2 for odd d,
// 0 for even d; |t-s| <= 362 < 512 so no wraparound; weights at lag m>512 fold
// back symmetrically -> weight depends only on |t-s|).
// Even-lag terms are exactly zero -> iterate only opposite-parity s (2x fewer
// terms). All 4 batches per thread via float4 LDS reads; per iteration the
// wave touches only two LDS addresses (parity groups) -> broadcast, no
// conflicts (round-3 SQ_LDS_BANK_CONFLICT == 0 confirmed).
// ---------------------------------------------------------------------------
__global__ __launch_bounds__(128) void iradon_filter_kernel(
        const float* __restrict__ x) {
    __shared__ f4    xs4[S_DIM];   // per-s, batch-interleaved
    __shared__ float wt[182];      // wt[k] = -2/(pi*(2k+1))^2

    const int b     = blockIdx.x;       // 0 .. 180*3-1
    const int a     = b / 3;
    const int chunk = b % 3;
    const int tid   = threadIdx.x;

    for (int s = tid; s < S_DIM; s += 128) {
        f4 v;
        v.x = x[(0 * S_DIM + s) * A_DIM + a];
        v.y = x[(1 * S_DIM + s) * A_DIM + a];
        v.z = x[(2 * S_DIM + s) * A_DIM + a];
        v.w = x[(3 * S_DIM + s) * A_DIM + a];
        xs4[s] = v;
    }
    for (int k = tid; k < 182; k += 128) {
        float d = (float)(2 * k + 1);
        wt[k] = -2.0f / (F_PI * F_PI * d * d);
    }
    __syncthreads();

    const int t = chunk * 128 + tid;
    if (t < S_DIM) {
        f4 acc = 0.5f * xs4[t];            // d == 0 term
        const int s0 = 1 - (t & 1);        // opposite parity of t
        #pragma unroll 4
        for (int s = s0; s < S_DIM; s += 2) {
            int d = s - t; d = (d < 0) ? -d : d;
            float w = wt[d >> 1];
            acc += w * xs4[s];             // 2x v_pk_fma_f32
        }
        g_yf4[a * S_P + 1 + t] = acc;
    }

    // zero guards for this angle: s = 0 and 364..367
    if (chunk == 0 && tid < 5) {
        int idx = (tid == 0) ? 0 : (363 + tid);
        g_yf4[a * S_P + idx] = (f4)0.0f;
    }
}

// ---------------------------------------------------------------------------
// Kernel 2: backprojection. pos = (j-128)*cos - (i-128)*sin + 181.
// Index math computed ONCE per (pixel, angle); applied to all 4 batches via
// two dwordx4 loads + packed-f32 lerp. Angle loop split 4 ways across the
// block's 4 waves (wave q handles angles [45q, 45q+45)) for 4 waves/SIMD
// occupancy; partial sums merged through LDS.
// Block = 256 thr = 32(j) x 2(i) pixels x 4 angle-quarters. Grid = 8 x 128.
// ---------------------------------------------------------------------------
__global__ __launch_bounds__(256) void iradon_backproject_kernel(
        float* __restrict__ out) {
    __shared__ float cs[A_DIM];
    __shared__ float sn[A_DIM];
    __shared__ f4 red[256];

    const int tid = threadIdx.x;
    if (tid < A_DIM) {
        float th = (float)tid * (F_PI / 180.0f);
        cs[tid] = cosf(th);
        sn[tid] = sinf(th);
    }
    __syncthreads();

    const int px = tid & 63;
    const int q  = tid >> 6;           // wave index = angle quarter (uniform/wave)
    const int tj = px & 31;
    const int ti = px >> 5;            // 0..1
    const int j  = blockIdx.x * 32 + tj;
    const int i  = blockIdx.y * 2 + ti;

    const float jj  = (float)(j - 128);
    const float nii = (float)(128 - i);    // -(i-128)

    f4 acc = (f4)0.0f;
    const int a0 = q * 45;
    #pragma unroll 3
    for (int m = 0; m < 45; ++m) {
        const int a = a0 + m;
        const float c = cs[a];             // broadcast LDS reads
        const float s = sn[a];
        float pos = fmaf(jj, c, fmaf(nii, s, 181.0f));
        float f   = floorf(pos);
        int   k   = (int)f;
        float w   = pos - f;
        const f4* __restrict__ col = g_yf4 + a * S_P + 1 + k;
        f4 v0 = col[0];                    // global_load_dwordx4, guards make
        f4 v1 = col[1];                    // these unconditionally in-bounds
        acc += v0 + w * (v1 - v0);         // packed-f32 lerp, all 4 batches
    }

    red[tid] = acc;
    __syncthreads();

    if (tid < 64) {
        f4 r = red[tid] + red[tid + 64] + red[tid + 128] + red[tid + 192];
        r *= (F_PI / 360.0f);
        const int jo = blockIdx.x * 32 + (tid & 31);
        const int io = blockIdx.y * 2 + (tid >> 5);
        const size_t p = (size_t)io * OUT_W + jo;
        out[p]              = r.x;
        out[p +     65536]  = r.y;
        out[p + 2 * 65536]  = r.z;
        out[p + 3 * 65536]  = r.w;
    }
}

extern "C" void kernel_launch(void* const* d_in, const int* in_sizes, int n_in,
                              void* d_out, int out_size, void* d_ws, size_t ws_size,
                              hipStream_t stream) {
    const float* x = (const float*)d_in[0];
    float* out = (float*)d_out;

    iradon_filter_kernel<<<dim3(A_DIM * 3), 128, 0, stream>>>(x);
    iradon_backproject_kernel<<<dim3(OUT_W / 32, OUT_W / 2, 1), 256, 0, stream>>>(out);
}

// Round 5
// 74.212 us; speedup vs baseline: 2.0495x; 1.0459x over previous
//
#include <hip/hip_runtime.h>

#define S_DIM 363      // GRID = ceil(sqrt(2)*256)
#define S_P   368      // padded stride: guard zero at [0], data at [1..363], zeros at [364..367]
#define A_DIM 180      // N_THETA
#define OUT_W 256
#define F_PI 3.14159265358979323846f

typedef float    f4 __attribute__((ext_vector_type(4)));
typedef _Float16 h4 __attribute__((ext_vector_type(4)));
union HU { uint2 u; h4 h; };

// Filtered sinogram, batch-packed as 4 x fp16 per (angle, sample) = 8 B.
// fp16 halves the backprojection's L1 line footprint vs f32x4; quantization
// adds ~3.5e-5 to the output (180-term random walk x pi/360) vs 3.4e-3 of
// threshold headroom. Zero guards at s=0 and s=364..367 keep all interp loads
// unconditionally in-bounds (pos in [-0.02,362.02] => k in [-1,362] =>
// indices k+1 in [0,363], k+2 in [1,364]), matching reference clip+mask.
// Fully rewritten (incl. guards) every call before kernel 2 reads it.
__device__ uint2 g_yh[A_DIM * S_P];

// ---------------------------------------------------------------------------
// Kernel 1: ramp filter as direct spatial convolution (exact rewrite of the
// reference FFT path: circular conv with g[0]=0.5, g[d]=-2/(pi*d)^2 odd d,
// 0 even d; |t-s| <= 362 < 512 so weight depends only on |t-s|).
// Parity pruning (even lags are zero) halves the terms; all 4 batches per
// thread via f4 LDS reads (per iter the wave touches only 2 LDS addresses ->
// broadcast, conflict-free — round-3 SQ_LDS_BANK_CONFLICT == 0).
// fp32 internal math, fp16x4 packed output.
// ---------------------------------------------------------------------------
__global__ __launch_bounds__(128) void iradon_filter_kernel(
        const float* __restrict__ x) {
    __shared__ f4    xs4[S_DIM];   // per-s, batch-interleaved
    __shared__ float wt[182];      // wt[k] = -2/(pi*(2k+1))^2

    const int b     = blockIdx.x;       // 0 .. 180*3-1
    const int a     = b / 3;
    const int chunk = b % 3;
    const int tid   = threadIdx.x;

    for (int s = tid; s < S_DIM; s += 128) {
        f4 v;
        v.x = x[(0 * S_DIM + s) * A_DIM + a];
        v.y = x[(1 * S_DIM + s) * A_DIM + a];
        v.z = x[(2 * S_DIM + s) * A_DIM + a];
        v.w = x[(3 * S_DIM + s) * A_DIM + a];
        xs4[s] = v;
    }
    for (int k = tid; k < 182; k += 128) {
        float d = (float)(2 * k + 1);
        wt[k] = -2.0f / (F_PI * F_PI * d * d);
    }
    __syncthreads();

    const int t = chunk * 128 + tid;
    if (t < S_DIM) {
        f4 acc = 0.5f * xs4[t];            // d == 0 term
        const int s0 = 1 - (t & 1);        // opposite parity of t
        #pragma unroll 4
        for (int s = s0; s < S_DIM; s += 2) {
            int d = s - t; d = (d < 0) ? -d : d;
            float w = wt[d >> 1];
            acc += w * xs4[s];             // 2x v_pk_fma_f32
        }
        HU p; p.h = __builtin_convertvector(acc, h4);
        g_yh[a * S_P + 1 + t] = p.u;
    }

    // zero guards for this angle: s = 0 and 364..367
    if (chunk == 0 && tid < 5) {
        int idx = (tid == 0) ? 0 : (363 + tid);
        g_yh[a * S_P + idx] = make_uint2(0u, 0u);
    }
}

// ---------------------------------------------------------------------------
// Kernel 2: backprojection. pos = (j-128)*cos - (i-128)*sin + 181.
// Index math once per (pixel, angle); both interp taps for all 4 batches are
// 16 B (two 8-B fp16x4 loads). Lerp accumulates in f32 via (float)half * f32
// FMAs (folds to v_fma_mix_f32). Angle loop split 4 ways across the block's
// 4 waves (4 waves/SIMD occupancy); partials merged through LDS.
// Block = 256 thr = 32(j) x 2(i) pixels x 4 angle-quarters. Grid = 8 x 128.
// ---------------------------------------------------------------------------
__global__ __launch_bounds__(256) void iradon_backproject_kernel(
        float* __restrict__ out) {
    __shared__ float cs[A_DIM];
    __shared__ float sn[A_DIM];
    __shared__ f4 red[256];

    const int tid = threadIdx.x;
    if (tid < A_DIM) {
        float th = (float)tid * (F_PI / 180.0f);
        cs[tid] = cosf(th);
        sn[tid] = sinf(th);
    }
    __syncthreads();

    const int px = tid & 63;
    const int q  = tid >> 6;           // wave index = angle quarter (uniform/wave)
    const int tj = px & 31;
    const int ti = px >> 5;            // 0..1
    const int j  = blockIdx.x * 32 + tj;
    const int i  = blockIdx.y * 2 + ti;

    const float jj  = (float)(j - 128);
    const float nii = (float)(128 - i);    // -(i-128)

    f4 acc = (f4)0.0f;
    const int a0 = q * 45;
    #pragma unroll 3
    for (int m = 0; m < 45; ++m) {
        const int a = a0 + m;
        const float c = cs[a];             // broadcast LDS reads
        const float s = sn[a];
        float pos = fmaf(jj, c, fmaf(nii, s, 181.0f));
        float f   = floorf(pos);
        int   k   = (int)f;
        float w1  = pos - f;
        float w0  = 1.0f - w1;
        const uint2* __restrict__ col = g_yh + a * S_P + 1 + k;
        HU u0; u0.u = col[0];              // sample k+1, guards make these
        HU u1; u1.u = col[1];              // unconditionally in-bounds
        acc.x = fmaf((float)u0.h.x, w0, fmaf((float)u1.h.x, w1, acc.x));
        acc.y = fmaf((float)u0.h.y, w0, fmaf((float)u1.h.y, w1, acc.y));
        acc.z = fmaf((float)u0.h.z, w0, fmaf((float)u1.h.z, w1, acc.z));
        acc.w = fmaf((float)u0.h.w, w0, fmaf((float)u1.h.w, w1, acc.w));
    }

    red[tid] = acc;
    __syncthreads();

    if (tid < 64) {
        f4 r = red[tid] + red[tid + 64] + red[tid + 128] + red[tid + 192];
        r *= (F_PI / 360.0f);
        const int jo = blockIdx.x * 32 + (tid & 31);
        const int io = blockIdx.y * 2 + (tid >> 5);
        const size_t p = (size_t)io * OUT_W + jo;
        out[p]              = r.x;
        out[p +     65536]  = r.y;
        out[p + 2 * 65536]  = r.z;
        out[p + 3 * 65536]  = r.w;
    }
}

extern "C" void kernel_launch(void* const* d_in, const int* in_sizes, int n_in,
                              void* d_out, int out_size, void* d_ws, size_t ws_size,
                              hipStream_t stream) {
    const float* x = (const float*)d_in[0];
    float* out = (float*)d_out;

    iradon_filter_kernel<<<dim3(A_DIM * 3), 128, 0, stream>>>(x);
    iradon_backproject_kernel<<<dim3(OUT_W / 32, OUT_W / 2, 1), 256, 0, stream>>>(out);
}

// Round 6
// 72.877 us; speedup vs baseline: 2.0870x; 1.0183x over previous
//
#include <hip/hip_runtime.h>

#define S_DIM 363      // GRID = ceil(sqrt(2)*256)
#define S_P   368      // padded per-angle stride of the paired layout
#define A_DIM 180      // N_THETA
#define OUT_W 256
#define F_PI 3.14159265358979323846f

typedef float    f4 __attribute__((ext_vector_type(4)));
typedef _Float16 h4 __attribute__((ext_vector_type(4)));
union HU  { uint2 u; h4 h; };
union HU2 { uint4 u; struct { h4 lo; h4 hi; } h; };

// Paired-tap filtered sinogram: g_pair[a*S_P + m] = (y[m-1], y[m]) for all 4
// batches as fp16 -> 16 B, 16-B aligned. Backprojection's two interp taps for
// all 4 batches come from ONE global_load_dwordx4: k = floor(pos) in [-1,362],
// load index k+1 in [0,363]; P[0] = (0, y[0]) and P[363] = (y[362], 0)
// reproduce the reference's clip+zero-weight edge semantics exactly.
// fp16 quantization adds ~3.5e-5 vs 3.4e-3 threshold headroom (verified R5).
// Fully rewritten every call before kernel 2 reads it.
__device__ uint4 g_pair[A_DIM * S_P];

// ---------------------------------------------------------------------------
// Kernel 1: ramp filter as direct spatial convolution (exact rewrite of the
// reference FFT path: circular conv, g[0]=0.5, g[d]=-2/(pi*d)^2 for odd d,
// 0 for even d; |t-s| <= 362 < 512 so weight depends only on |t-s|).
// One block per angle (384 thr): column staged ONCE (round-5 staged it 3x),
// parity pruning halves the taps, all 4 batches per thread via f4 LDS reads
// (wave touches 2 LDS addresses/iter -> broadcast, conflict-free).
// Output assembled into the paired fp16 layout through an LDS round-trip.
// ---------------------------------------------------------------------------
__global__ __launch_bounds__(384) void iradon_filter_kernel(
        const float* __restrict__ x) {
    __shared__ f4    xs4[S_DIM];   // per-s, batch-interleaved f32
    __shared__ float wt[182];      // wt[k] = -2/(pi*(2k+1))^2
    __shared__ h4    ys[366];      // ys[0]=0, ys[1+t]=fp16(y[t]), ys[364]=0

    const int a   = blockIdx.x;    // 0..179
    const int tid = threadIdx.x;

    if (tid < S_DIM) {
        f4 v;
        v.x = x[(0 * S_DIM + tid) * A_DIM + a];
        v.y = x[(1 * S_DIM + tid) * A_DIM + a];
        v.z = x[(2 * S_DIM + tid) * A_DIM + a];
        v.w = x[(3 * S_DIM + tid) * A_DIM + a];
        xs4[tid] = v;
    }
    if (tid < 182) {
        float d = (float)(2 * tid + 1);
        wt[tid] = -2.0f / (F_PI * F_PI * d * d);
    }
    if (tid == 363) ys[0]   = (h4)(_Float16)0.0f;   // guard y[-1]
    if (tid == 364) ys[364] = (h4)(_Float16)0.0f;   // guard y[363]
    __syncthreads();

    if (tid < S_DIM) {
        f4 acc = 0.5f * xs4[tid];          // d == 0 term
        const int s0 = 1 - (tid & 1);      // opposite parity of t
        #pragma unroll 4
        for (int s = s0; s < S_DIM; s += 2) {
            int d = s - tid; d = (d < 0) ? -d : d;
            float w = wt[d >> 1];
            acc += w * xs4[s];             // 2x v_pk_fma_f32
        }
        ys[1 + tid] = __builtin_convertvector(acc, h4);
    }
    __syncthreads();

    if (tid < 364) {                       // P[m] = (y[m-1], y[m])
        HU2 p;
        p.h.lo = ys[tid];
        p.h.hi = ys[tid + 1];
        g_pair[a * S_P + tid] = p.u;
    }
}

// ---------------------------------------------------------------------------
// Kernel 2: backprojection. pos = (j-128)*cos - (i-128)*sin + 181.
// Index math once per (pixel, angle); ONE 16-B aligned dwordx4 load delivers
// both interp taps for all 4 batches. f32 accumulation via (float)half * f32
// FMAs (v_fma_mix_f32). Angle loop split 4 ways across the block's 4 waves
// (4 waves/SIMD occupancy); partials merged through LDS.
// Block = 256 thr = 32(j) x 2(i) pixels x 4 angle-quarters. Grid = 8 x 128.
// ---------------------------------------------------------------------------
__global__ __launch_bounds__(256) void iradon_backproject_kernel(
        float* __restrict__ out) {
    __shared__ float cs[A_DIM];
    __shared__ float sn[A_DIM];
    __shared__ f4 red[256];

    const int tid = threadIdx.x;
    if (tid < A_DIM) {
        float th = (float)tid * (F_PI / 180.0f);
        cs[tid] = cosf(th);
        sn[tid] = sinf(th);
    }
    __syncthreads();

    const int px = tid & 63;
    const int q  = tid >> 6;           // wave index = angle quarter (uniform/wave)
    const int tj = px & 31;
    const int ti = px >> 5;            // 0..1
    const int j  = blockIdx.x * 32 + tj;
    const int i  = blockIdx.y * 2 + ti;

    const float jj  = (float)(j - 128);
    const float nii = (float)(128 - i);    // -(i-128)

    f4 acc = (f4)0.0f;
    const int a0 = q * 45;
    #pragma unroll 3
    for (int m = 0; m < 45; ++m) {
        const int a = a0 + m;
        const float c = cs[a];             // broadcast LDS reads
        const float s = sn[a];
        float pos = fmaf(jj, c, fmaf(nii, s, 181.0f));
        float f   = floorf(pos);
        int   k1  = (int)f + 1;            // in [0, 363]
        float w1  = pos - f;
        float w0  = 1.0f - w1;
        HU2 v; v.u = g_pair[a * S_P + k1]; // one dwordx4: (y[k], y[k+1]) x4 batches
        acc.x = fmaf((float)v.h.lo.x, w0, fmaf((float)v.h.hi.x, w1, acc.x));
        acc.y = fmaf((float)v.h.lo.y, w0, fmaf((float)v.h.hi.y, w1, acc.y));
        acc.z = fmaf((float)v.h.lo.z, w0, fmaf((float)v.h.hi.z, w1, acc.z));
        acc.w = fmaf((float)v.h.lo.w, w0, fmaf((float)v.h.hi.w, w1, acc.w));
    }

    red[tid] = acc;
    __syncthreads();

    if (tid < 64) {
        f4 r = red[tid] + red[tid + 64] + red[tid + 128] + red[tid + 192];
        r *= (F_PI / 360.0f);
        const int jo = blockIdx.x * 32 + (tid & 31);
        const int io = blockIdx.y * 2 + (tid >> 5);
        const size_t p = (size_t)io * OUT_W + jo;
        out[p]              = r.x;
        out[p +     65536]  = r.y;
        out[p + 2 * 65536]  = r.z;
        out[p + 3 * 65536]  = r.w;
    }
}

extern "C" void kernel_launch(void* const* d_in, const int* in_sizes, int n_in,
                              void* d_out, int out_size, void* d_ws, size_t ws_size,
                              hipStream_t stream) {
    const float* x = (const float*)d_in[0];
    float* out = (float*)d_out;

    iradon_filter_kernel<<<dim3(A_DIM), 384, 0, stream>>>(x);
    iradon_backproject_kernel<<<dim3(OUT_W / 32, OUT_W / 2, 1), 256, 0, stream>>>(out);
}